// Round 8
// baseline (75.193 us; speedup 1.0000x reference)
//
#include <hip/hip_runtime.h>
#include <hip/hip_bf16.h>

#define NN 4096
#define IN_DIM 512
#define OUT_DIM 256
#define NH 4
#define HD 64
#define NEG_SLOPE 0.2f
#define LN_EPS 1e-5f
#define LOG2E 1.4426950408889634f
#define DBIAS 1024.0f

typedef __attribute__((ext_vector_type(8))) short short8;
typedef __attribute__((ext_vector_type(4))) float f32x4;
typedef unsigned short u16;
typedef unsigned int u32;
typedef unsigned long long u64;
typedef unsigned char u8;

// ---------------------------------------------------------------------------
// K0: pack (adj>0)|I into bitmask [NN][NN/8 B]; blocks < 128 also transpose
// W [H][K][D] f32 -> Wt [h*64+d][512] bf16.
// ---------------------------------------------------------------------------
__global__ __launch_bounds__(1024) void k0_pack(
    const int* __restrict__ adj, u8* __restrict__ mask,
    const float* __restrict__ W, u16* __restrict__ Wt)
{
  const int b = blockIdx.x;
  const int t = threadIdx.x;
#pragma unroll
  for (int it = 0; it < 4; ++it) {
    const int row = b * 8 + it * 2 + (t >> 9);
    const int byte = t & 511;
    const int j0 = byte * 8;
    const int4 v0 = *reinterpret_cast<const int4*>(adj + (size_t)row * NN + j0);
    const int4 v1 = *reinterpret_cast<const int4*>(adj + (size_t)row * NN + j0 + 4);
    const int vv[8] = {v0.x, v0.y, v0.z, v0.w, v1.x, v1.y, v1.z, v1.w};
    u32 bbits = 0;
#pragma unroll
    for (int c = 0; c < 8; ++c)
      if ((vv[c] > 0) || (row == j0 + c)) bbits |= (1u << c);
    mask[(size_t)row * (NN / 8) + byte] = (u8)bbits;
  }
  if (b < 128) {
    const int n = b * 1024 + t;      // n = h*2^15 + k*2^6 + d
    const int d = n & 63;
    const int k = (n >> 6) & 511;
    const int h = n >> 15;
    __hip_bfloat16 bv = __float2bfloat16(W[n]);
    Wt[(size_t)(h * HD + d) * IN_DIM + k] = *reinterpret_cast<const u16*>(&bv);
  }
}

// ---------------------------------------------------------------------------
// K1: MFMA projection, K-split for occupancy. grid 256 (16-row tiles),
// block 1024 = 16 waves: wv = kq*4 + h (head h, K-quarter kq of 128).
// Stage x[16][512] bf16 in LDS (XOR-swizzled), 1 barrier; each wave does
// 4 K-steps {1 ds_read_b128 A + 4 B 16B loads (L2 Wt) + 4 MFMA}; K-quarter
// partials merged via padded LDS; kq=0 waves run the epilogue:
// WxT direct store, s/d scores (x LOG2E), per-head maxd via atomicMax
// (d + 1024 > 0, so float bits order as uint).
// ---------------------------------------------------------------------------
__global__ __launch_bounds__(1024) void k1_proj(
    const float* __restrict__ x, const u16* __restrict__ Wt,
    const float* __restrict__ a,
    u16* __restrict__ WxT,
    float* __restrict__ s_src,
    float* __restrict__ d_dst,
    u32* __restrict__ maxd_u)
{
  const int i0 = blockIdx.x * 16;
  const int t = threadIdx.x;
  const int wv = t >> 6;
  const int h = wv & 3;
  const int kq = wv >> 2;
  const int lane = t & 63;
  const int rloc = lane & 15;
  const int g = lane >> 4;

  __shared__ u16 xl[16 * 512];          // [row][unit*8], XOR-swizzled units
  __shared__ float lacc[12][16][66];    // kq=1..3 partials, pad 66

  // ---- stage x tile: wave = row, lane = 16B unit ----
  {
    const int r = t >> 6;
    const int u = t & 63;
    const float* xr = x + (size_t)(i0 + r) * IN_DIM + u * 8;
    const float4 lo = *reinterpret_cast<const float4*>(xr);
    const float4 hi = *reinterpret_cast<const float4*>(xr + 4);
    const float fv[8] = {lo.x, lo.y, lo.z, lo.w, hi.x, hi.y, hi.z, hi.w};
    u16 us[8];
#pragma unroll
    for (int e = 0; e < 8; ++e) {
      __hip_bfloat16 bv = __float2bfloat16(fv[e]);
      us[e] = *reinterpret_cast<const u16*>(&bv);
    }
    const int phys = (u & 56) | ((u & 7) ^ (r & 7));
    uint4 pk;
    pk.x = (u32)us[0] | ((u32)us[1] << 16);
    pk.y = (u32)us[2] | ((u32)us[3] << 16);
    pk.z = (u32)us[4] | ((u32)us[5] << 16);
    pk.w = (u32)us[6] | ((u32)us[7] << 16);
    *reinterpret_cast<uint4*>(&xl[r * 512 + phys * 8]) = pk;
  }
  __syncthreads();

  // ---- MFMA: this wave's K-quarter ----
  f32x4 acc[4] = {};
  const u16* wb = Wt + (size_t)(h * HD + rloc) * IN_DIM + kq * 128;
#pragma unroll
  for (int ks = 0; ks < 4; ++ks) {
    const int u = kq * 16 + ks * 4 + g;
    const int phys = (u & 56) | ((u & 7) ^ (rloc & 7));
    const short8 af = *reinterpret_cast<const short8*>(&xl[rloc * 512 + phys * 8]);
#pragma unroll
    for (int dt = 0; dt < 4; ++dt) {
      const short8 bf = *reinterpret_cast<const short8*>(
          wb + (size_t)dt * 16 * IN_DIM + ks * 32 + g * 8);
      acc[dt] = __builtin_amdgcn_mfma_f32_16x16x32_bf16(af, bf, acc[dt], 0, 0, 0);
    }
  }

  // ---- merge K-quarters ----
  if (kq != 0) {
#pragma unroll
    for (int dt = 0; dt < 4; ++dt)
#pragma unroll
      for (int q = 0; q < 4; ++q)
        lacc[wv - 4][g * 4 + q][dt * 16 + rloc] = acc[dt][q];
  }
  __syncthreads();
  if (kq == 0) {
#pragma unroll
    for (int dt = 0; dt < 4; ++dt)
#pragma unroll
      for (int q = 0; q < 4; ++q)
        acc[dt][q] += lacc[h][g * 4 + q][dt * 16 + rloc] +
                      lacc[h + 4][g * 4 + q][dt * 16 + rloc] +
                      lacc[h + 8][g * 4 + q][dt * 16 + rloc];

    // ---- epilogue: WxT direct store ----
#pragma unroll
    for (int dt = 0; dt < 4; ++dt) {
      u16 us[4];
#pragma unroll
      for (int q = 0; q < 4; ++q) {
        __hip_bfloat16 bv = __float2bfloat16(acc[dt][q]);
        us[q] = *reinterpret_cast<const u16*>(&bv);
      }
      ushort4 pk = {us[0], us[1], us[2], us[3]};
      *reinterpret_cast<ushort4*>(
          WxT + (size_t)(h * HD + dt * 16 + rloc) * NN + i0 + g * 4) = pk;
    }

    // ---- scores ----
    float as_v[4], ad_v[4];
#pragma unroll
    for (int dt = 0; dt < 4; ++dt) {
      as_v[dt] = a[(size_t)h * 2 * HD + dt * 16 + rloc];
      ad_v[dt] = a[(size_t)h * 2 * HD + HD + dt * 16 + rloc];
    }
    float sv[4], dv[4];
#pragma unroll
    for (int q = 0; q < 4; ++q) {
      float s = 0.f, d = 0.f;
#pragma unroll
      for (int dt = 0; dt < 4; ++dt) {
        s = fmaf(acc[dt][q], as_v[dt], s);
        d = fmaf(acc[dt][q], ad_v[dt], d);
      }
      sv[q] = s; dv[q] = d;
    }
#pragma unroll
    for (int mm = 8; mm >= 1; mm >>= 1) {
#pragma unroll
      for (int q = 0; q < 4; ++q) {
        sv[q] += __shfl_xor(sv[q], mm);
        dv[q] += __shfl_xor(dv[q], mm);
      }
    }
    if (rloc == 0) {
#pragma unroll
      for (int q = 0; q < 4; ++q) {
        const int i = i0 + g * 4 + q;
        s_src[(size_t)h * NN + i] = sv[q] * LOG2E;
        d_dst[(size_t)h * NN + i] = dv[q] * LOG2E;
      }
    }
    // per-head max of d (log2 domain): bias positive, bits order as uint
    float dm = fmaxf(fmaxf(dv[0], dv[1]), fmaxf(dv[2], dv[3])) * LOG2E + DBIAS;
    dm = fmaxf(dm, __shfl_xor(dm, 16));
    dm = fmaxf(dm, __shfl_xor(dm, 32));
    if (lane == 0) atomicMax(maxd_u + h, __float_as_uint(dm));
  }
}

// ---------------------------------------------------------------------------
// K3: masked rank-1 softmax + PV, LDS-staged & double-buffered.
// grid (32 i-blocks, 4 heads, 4 j-quarters), block 512 = 8 waves,
// wave = 16 rows; j window = full 1024 of the quarter, 8 tiles of 128.
// ---------------------------------------------------------------------------
__global__ __launch_bounds__(512, 4) void k3_attn(
    const u8* __restrict__ mask,
    const u16* __restrict__ WxT,
    const float* __restrict__ s_src, const float* __restrict__ d_dst,
    const u32* __restrict__ maxd_u,
    u16* __restrict__ Pp, float* __restrict__ Sp)
{
  const int bx = blockIdx.x;
  const int h = blockIdx.y;
  const int jq = blockIdx.z;
  const int t = threadIdx.x;
  const int wv = t >> 6;
  const int lane = t & 63;
  const int rloc = lane & 15;
  const int g = lane >> 4;
  const int i_base = bx * 128 + wv * 16;
  const int i = i_base + rloc;

  __shared__ u16 wt[2][64 * 128];   // [buf][row*128 + unit*8], XOR-swizzled
  __shared__ u32 mk[128 * 36];      // [row][36 words] (32 used, pad 4)

  const float md = __uint_as_float(maxd_u[h]) - DBIAS;
  const float si0 = s_src[(size_t)h * NN + i];
  const float e00 = si0 + md;
  const float m0 = fmaxf(e00, NEG_SLOPE * e00);
  const float sa0 = si0 - m0, sb0 = fmaf(NEG_SLOPE, si0, -m0);

  const float* dg = d_dst + (size_t)h * NN + jq * 1024;
  const u16* wsrc = WxT + (size_t)(h * HD) * NN + jq * 1024;

  const int r0 = t >> 4;
  const int un = t & 15;
  const int up = un ^ (r0 & 7);

  // ---- prologue: mask (once) + WxT tile 0 ----
#pragma unroll
  for (int k = 0; k < 2; ++k) {
    const int n = k * 512 + t;
    const int row = n >> 3;
    const int quad = n & 7;
    const uint4 mv = *reinterpret_cast<const uint4*>(
        mask + ((size_t)(bx * 128 + row) * (NN / 8)) + jq * 128 + quad * 16);
    *reinterpret_cast<uint4*>(&mk[row * 36 + quad * 4]) = mv;
  }
  {
    const uint4 s0 = *reinterpret_cast<const uint4*>(wsrc + (size_t)r0 * NN + un * 8);
    const uint4 s1 = *reinterpret_cast<const uint4*>(wsrc + (size_t)(r0 + 32) * NN + un * 8);
    *reinterpret_cast<uint4*>(&wt[0][r0 * 128 + up * 8]) = s0;
    *reinterpret_cast<uint4*>(&wt[0][(r0 + 32) * 128 + up * 8]) = s1;
  }
  __syncthreads();

  f32x4 acc0[4] = {};
  f32x4 accs0 = {};
  short8 ones;
#pragma unroll
  for (int e = 0; e < 8; ++e) ones[e] = (short)0x3F80;

  int buf = 0;
  for (int tile = 0; tile < 8; ++tile) {
    uint4 n0, n1;
    const bool pf = (tile < 7);
    if (pf) {
      n0 = *reinterpret_cast<const uint4*>(
          wsrc + (size_t)r0 * NN + (tile + 1) * 128 + un * 8);
      n1 = *reinterpret_cast<const uint4*>(
          wsrc + (size_t)(r0 + 32) * NN + (tile + 1) * 128 + un * 8);
    }

    const uint4 mq0 = *reinterpret_cast<const uint4*>(
        &mk[(wv * 16 + rloc) * 36 + tile * 4]);
#pragma unroll
    for (int ks = 0; ks < 4; ++ks) {
      short8 bfr[4];
#pragma unroll
      for (int dt = 0; dt < 4; ++dt) {
        const int row = dt * 16 + rloc;
        const int unit = (ks * 4 + g) ^ (row & 7);
        bfr[dt] = *reinterpret_cast<const short8*>(&wt[buf][row * 128 + unit * 8]);
      }
      const int jloc = tile * 128 + ks * 32 + g * 8;
      const float4 d0 = *reinterpret_cast<const float4*>(dg + jloc);
      const float4 d1 = *reinterpret_cast<const float4*>(dg + jloc + 4);
      const float dvv[8] = {d0.x, d0.y, d0.z, d0.w, d1.x, d1.y, d1.z, d1.w};
      const u32 mw0 = (ks == 0) ? mq0.x : (ks == 1) ? mq0.y : (ks == 2) ? mq0.z : mq0.w;
      const u32 mb0 = (mw0 >> (g * 8)) & 0xffu;
      short8 af0;
#pragma unroll
      for (int e = 0; e < 8; ++e) {
        const float dj = dvv[e];
        float x0 = fmaxf(sa0 + dj, fmaf(NEG_SLOPE, dj, sb0));
        x0 = (mb0 & (1u << e)) ? x0 : -400.f;
        float p0;
        asm("v_exp_f32 %0, %1" : "=v"(p0) : "v"(x0));   // 2^x
        __hip_bfloat16 b0 = __float2bfloat16(p0);
        af0[e] = *reinterpret_cast<const short*>(&b0);
      }
#pragma unroll
      for (int dt = 0; dt < 4; ++dt)
        acc0[dt] = __builtin_amdgcn_mfma_f32_16x16x32_bf16(af0, bfr[dt], acc0[dt], 0, 0, 0);
      accs0 = __builtin_amdgcn_mfma_f32_16x16x32_bf16(af0, ones, accs0, 0, 0, 0);
    }

    if (pf) {
      *reinterpret_cast<uint4*>(&wt[buf ^ 1][r0 * 128 + up * 8]) = n0;
      *reinterpret_cast<uint4*>(&wt[buf ^ 1][(r0 + 32) * 128 + up * 8]) = n1;
    }
    __syncthreads();
    buf ^= 1;
  }

  // ---- epilogue: bf16 partial tile + row sums ----
  u16* Pb = Pp + (size_t)jq * NN * OUT_DIM;
#pragma unroll
  for (int dt = 0; dt < 4; ++dt)
#pragma unroll
    for (int q = 0; q < 4; ++q) {
      __hip_bfloat16 v0 = __float2bfloat16(acc0[dt][q]);
      Pb[(size_t)(i_base + g * 4 + q) * OUT_DIM + h * HD + dt * 16 + rloc] =
          *reinterpret_cast<const u16*>(&v0);
    }
  if (rloc == 0)
    *reinterpret_cast<f32x4*>(&Sp[((size_t)jq * NH + h) * NN + i_base + g * 4]) = accs0;
}

// ---------------------------------------------------------------------------
// K4: merge 4 j-quarter partials, normalize, ELU, LayerNorm, store.
// ---------------------------------------------------------------------------
__global__ __launch_bounds__(256) void k4_final(
    const u16* __restrict__ Pp, const float* __restrict__ Sp,
    const float* __restrict__ gamma, const float* __restrict__ beta,
    float* __restrict__ out)
{
  const int i0 = blockIdx.x * 16;
  const int t = threadIdx.x;
  const int wv = t >> 6;
  const int lane = t & 63;
  const int c0 = lane * 4;
  const int h = lane >> 4;

  const float4 gm = *reinterpret_cast<const float4*>(gamma + c0);
  const float4 bt = *reinterpret_cast<const float4*>(beta + c0);

  for (int rr = 0; rr < 4; ++rr) {
    const int i = i0 + wv * 4 + rr;
    float v[4] = {0.f, 0.f, 0.f, 0.f};
    float denom = 0.f;
#pragma unroll
    for (int q = 0; q < 4; ++q) {
      const ushort4 pv = *reinterpret_cast<const ushort4*>(
          Pp + (size_t)q * NN * OUT_DIM + (size_t)i * OUT_DIM + c0);
      v[0] += __uint_as_float((u32)pv.x << 16);
      v[1] += __uint_as_float((u32)pv.y << 16);
      v[2] += __uint_as_float((u32)pv.z << 16);
      v[3] += __uint_as_float((u32)pv.w << 16);
      denom += Sp[((size_t)q * NH + h) * NN + i];
    }
    const float inv = 1.f / denom;
    float sum = 0.f, sq = 0.f;
#pragma unroll
    for (int q2 = 0; q2 < 4; ++q2) {
      float xx = v[q2] * inv;
      xx = (xx > 0.f) ? xx : expm1f(xx);
      v[q2] = xx;
      sum += xx;
      sq += xx * xx;
    }
#pragma unroll
    for (int mm = 32; mm >= 1; mm >>= 1) {
      sum += __shfl_xor(sum, mm);
      sq += __shfl_xor(sq, mm);
    }
    const float mu = sum * (1.f / OUT_DIM);
    const float var = sq * (1.f / OUT_DIM) - mu * mu;
    const float rs = rsqrtf(var + LN_EPS);
    float4 o;
    o.x = (v[0] - mu) * rs * gm.x + bt.x;
    o.y = (v[1] - mu) * rs * gm.y + bt.y;
    o.z = (v[2] - mu) * rs * gm.z + bt.z;
    o.w = (v[3] - mu) * rs * gm.w + bt.w;
    *reinterpret_cast<float4*>(out + (size_t)i * OUT_DIM + c0) = o;
  }
}

extern "C" void kernel_launch(void* const* d_in, const int* in_sizes, int n_in,
                              void* d_out, int out_size, void* d_ws, size_t ws_size,
                              hipStream_t stream) {
  const float* x = (const float*)d_in[0];
  const int* adj = (const int*)d_in[1];
  const float* W = (const float*)d_in[2];
  const float* a = (const float*)d_in[3];
  const float* gamma = (const float*)d_in[4];
  const float* beta = (const float*)d_in[5];
  float* out = (float*)d_out;

  char* ws = (char*)d_ws;
  size_t off = 0;
  u16* WxT = (u16*)(ws + off);        off += (size_t)NH * HD * NN * 2;          // 2 MiB
  float* s_src = (float*)(ws + off);  off += (size_t)NH * NN * 4;               // 64 KiB
  float* d_dst = (float*)(ws + off);  off += (size_t)NH * NN * 4;               // 64 KiB
  u32* maxd_u = (u32*)(ws + off);     off += 256;
  u8* mask = (u8*)(ws + off);         off += (size_t)NN * (NN / 8);             // 2 MiB
  u16* Pp = (u16*)(ws + off);         off += (size_t)4 * NN * OUT_DIM * 2;      // 8 MiB (bf16)
  float* Sp = (float*)(ws + off);     off += (size_t)4 * NH * NN * 4;           // 256 KiB
  u16* Wt = (u16*)(ws + off);         off += (size_t)NH * HD * IN_DIM * 2;      // 256 KiB

  hipMemsetAsync(maxd_u, 0, NH * sizeof(u32), stream);
  k0_pack<<<dim3(512), dim3(1024), 0, stream>>>(adj, mask, W, Wt);
  k1_proj<<<dim3(256), dim3(1024), 0, stream>>>(x, Wt, a, WxT, s_src, d_dst, maxd_u);
  k3_attn<<<dim3(32, NH, 4), dim3(512), 0, stream>>>(mask, WxT, s_src, d_dst,
                                                     maxd_u, Pp, Sp);
  k4_final<<<dim3(256), dim3(256), 0, stream>>>(Pp, Sp, gamma, beta, out);
}

// Round 9
// 68.077 us; speedup vs baseline: 1.1045x; 1.1045x over previous
//
#include <hip/hip_runtime.h>
#include <hip/hip_bf16.h>

#define NN 4096
#define IN_DIM 512
#define OUT_DIM 256
#define NH 4
#define HD 64
#define NEG_SLOPE 0.2f
#define LN_EPS 1e-5f
#define LOG2E 1.4426950408889634f
#define DBIAS 1024.0f

typedef __attribute__((ext_vector_type(8))) short short8;
typedef __attribute__((ext_vector_type(4))) float f32x4;
typedef unsigned short u16;
typedef unsigned int u32;
typedef unsigned char u8;

// ---------------------------------------------------------------------------
// K0: pack (adj>0)|I into bitmask [NN][NN/8 B]; blocks < 128 also transpose
// W [H][K][D] f32 -> Wt [h*64+d][512] bf16. Block 0 zeroes maxd_u (consumed
// by k1's atomicMax; k1 is stream-ordered after k0).
// ---------------------------------------------------------------------------
__global__ __launch_bounds__(1024) void k0_pack(
    const int* __restrict__ adj, u8* __restrict__ mask,
    const float* __restrict__ W, u16* __restrict__ Wt,
    u32* __restrict__ maxd_u)
{
  const int b = blockIdx.x;
  const int t = threadIdx.x;
  if (b == 0 && t < NH) maxd_u[t] = 0u;
#pragma unroll
  for (int it = 0; it < 4; ++it) {
    const int row = b * 8 + it * 2 + (t >> 9);
    const int byte = t & 511;
    const int j0 = byte * 8;
    const int4 v0 = *reinterpret_cast<const int4*>(adj + (size_t)row * NN + j0);
    const int4 v1 = *reinterpret_cast<const int4*>(adj + (size_t)row * NN + j0 + 4);
    const int vv[8] = {v0.x, v0.y, v0.z, v0.w, v1.x, v1.y, v1.z, v1.w};
    u32 bbits = 0;
#pragma unroll
    for (int c = 0; c < 8; ++c)
      if ((vv[c] > 0) || (row == j0 + c)) bbits |= (1u << c);
    mask[(size_t)row * (NN / 8) + byte] = (u8)bbits;
  }
  if (b < 128) {
    const int n = b * 1024 + t;      // n = h*2^15 + k*2^6 + d
    const int d = n & 63;
    const int k = (n >> 6) & 511;
    const int h = n >> 15;
    __hip_bfloat16 bv = __float2bfloat16(W[n]);
    Wt[(size_t)(h * HD + d) * IN_DIM + k] = *reinterpret_cast<const u16*>(&bv);
  }
}

// ---------------------------------------------------------------------------
// K1: MFMA projection, all-LDS inner loop. grid 256 = (head h = b>>6,
// 64-row tile i0 = (b&63)*64), block 256 = 4 waves (wave = 16-row subtile).
// Stage x tile (64x512 bf16) AND Wt head-slice (64x512 bf16) into LDS,
// both XOR-swizzled on 16B units; 1 barrier; 16 K-steps of pure
// {ds_read A + 4x ds_read B + 4 MFMA}. Epilogue: WxT direct store, s/d
// scores (xLOG2E), per-head maxd via atomicMax on biased float bits.
// LDS = 128 KiB (1 block/CU).
// ---------------------------------------------------------------------------
__global__ __launch_bounds__(256) void k1_proj(
    const float* __restrict__ x, const u16* __restrict__ Wt,
    const float* __restrict__ a,
    u16* __restrict__ WxT,
    float* __restrict__ s_src,
    float* __restrict__ d_dst,
    u32* __restrict__ maxd_u)
{
  const int b = blockIdx.x;
  const int h = b >> 6;
  const int i0 = (b & 63) * 64;
  const int t = threadIdx.x;
  const int wv = t >> 6;
  const int lane = t & 63;
  const int rloc = lane & 15;
  const int g = lane >> 4;

  __shared__ u16 xl[64 * 512];   // 64 KiB: x tile, [row][unit swizzled]
  __shared__ u16 wb[64 * 512];   // 64 KiB: Wt slice, [drow][unit swizzled]

  // ---- stage: wave wv handles rows [wv*16, wv*16+16); lane = 16B unit ----
  {
    const int u = lane;
#pragma unroll
    for (int jj = 0; jj < 16; ++jj) {
      const int r = wv * 16 + jj;
      const int phys = (u & 56) | ((u & 7) ^ (r & 7));
      // x row (f32 -> bf16)
      const float* xr = x + (size_t)(i0 + r) * IN_DIM + u * 8;
      const float4 lo = *reinterpret_cast<const float4*>(xr);
      const float4 hi = *reinterpret_cast<const float4*>(xr + 4);
      const float fv[8] = {lo.x, lo.y, lo.z, lo.w, hi.x, hi.y, hi.z, hi.w};
      u16 us[8];
#pragma unroll
      for (int e = 0; e < 8; ++e) {
        __hip_bfloat16 bv = __float2bfloat16(fv[e]);
        us[e] = *reinterpret_cast<const u16*>(&bv);
      }
      uint4 pk;
      pk.x = (u32)us[0] | ((u32)us[1] << 16);
      pk.y = (u32)us[2] | ((u32)us[3] << 16);
      pk.z = (u32)us[4] | ((u32)us[5] << 16);
      pk.w = (u32)us[6] | ((u32)us[7] << 16);
      *reinterpret_cast<uint4*>(&xl[r * 512 + phys * 8]) = pk;
      // Wt row (already bf16): plain copy
      const uint4 wsv = *reinterpret_cast<const uint4*>(
          Wt + (size_t)(h * HD + r) * IN_DIM + u * 8);
      *reinterpret_cast<uint4*>(&wb[r * 512 + phys * 8]) = wsv;
    }
  }
  __syncthreads();

  // ---- MFMA loop: wave's 16-row subtile, all-LDS ----
  f32x4 acc[4] = {};
  const int rbase = wv * 16;
#pragma unroll
  for (int ks = 0; ks < 16; ++ks) {
    const int u = ks * 4 + g;
    const int ar = rbase + rloc;
    const int aphys = (u & 56) | ((u & 7) ^ (ar & 7));
    const short8 af = *reinterpret_cast<const short8*>(&xl[ar * 512 + aphys * 8]);
#pragma unroll
    for (int dt = 0; dt < 4; ++dt) {
      const int br = dt * 16 + rloc;
      const int bphys = (u & 56) | ((u & 7) ^ (br & 7));
      const short8 bf = *reinterpret_cast<const short8*>(&wb[br * 512 + bphys * 8]);
      acc[dt] = __builtin_amdgcn_mfma_f32_16x16x32_bf16(af, bf, acc[dt], 0, 0, 0);
    }
  }

  // ---- epilogue: WxT direct store (acc[dt][q] = C[i=g*4+q][d=dt*16+rloc]) ----
#pragma unroll
  for (int dt = 0; dt < 4; ++dt) {
    u16 us[4];
#pragma unroll
    for (int q = 0; q < 4; ++q) {
      __hip_bfloat16 bv = __float2bfloat16(acc[dt][q]);
      us[q] = *reinterpret_cast<const u16*>(&bv);
    }
    ushort4 pk = {us[0], us[1], us[2], us[3]};
    *reinterpret_cast<ushort4*>(
        WxT + (size_t)(h * HD + dt * 16 + rloc) * NN + i0 + rbase + g * 4) = pk;
  }

  // ---- scores ----
  float as_v[4], ad_v[4];
#pragma unroll
  for (int dt = 0; dt < 4; ++dt) {
    as_v[dt] = a[(size_t)h * 2 * HD + dt * 16 + rloc];
    ad_v[dt] = a[(size_t)h * 2 * HD + HD + dt * 16 + rloc];
  }
  float sv[4], dv[4];
#pragma unroll
  for (int q = 0; q < 4; ++q) {
    float s = 0.f, d = 0.f;
#pragma unroll
    for (int dt = 0; dt < 4; ++dt) {
      s = fmaf(acc[dt][q], as_v[dt], s);
      d = fmaf(acc[dt][q], ad_v[dt], d);
    }
    sv[q] = s; dv[q] = d;
  }
#pragma unroll
  for (int mm = 8; mm >= 1; mm >>= 1) {
#pragma unroll
    for (int q = 0; q < 4; ++q) {
      sv[q] += __shfl_xor(sv[q], mm);
      dv[q] += __shfl_xor(dv[q], mm);
    }
  }
  if (rloc == 0) {
#pragma unroll
    for (int q = 0; q < 4; ++q) {
      const int i = i0 + rbase + g * 4 + q;
      s_src[(size_t)h * NN + i] = sv[q] * LOG2E;
      d_dst[(size_t)h * NN + i] = dv[q] * LOG2E;
    }
  }
  float dm = fmaxf(fmaxf(dv[0], dv[1]), fmaxf(dv[2], dv[3])) * LOG2E + DBIAS;
#pragma unroll
  for (int mm = 8; mm >= 1; mm >>= 1) dm = fmaxf(dm, __shfl_xor(dm, mm));
  if (rloc == 0) atomicMax(maxd_u + h, __float_as_uint(dm));
}

// ---------------------------------------------------------------------------
// K3: masked rank-1 softmax (log2 domain) + PV (bf16 MFMA), LDS-staged &
// double-buffered. grid (16 i-blocks, 4 heads, 4 j-quarters), block 512 =
// 8 waves, wave = 32 rows (two A-frag row sets sharing B ds_reads).
// [round-7 geometry, verified]
// ---------------------------------------------------------------------------
__global__ __launch_bounds__(512) void k3_attn(
    const u8* __restrict__ mask,
    const u16* __restrict__ WxT,
    const float* __restrict__ s_src, const float* __restrict__ d_dst,
    const u32* __restrict__ maxd_u,
    u16* __restrict__ Pp, float* __restrict__ Sp)
{
  const int bx = blockIdx.x;
  const int h = blockIdx.y;
  const int jq = blockIdx.z;
  const int t = threadIdx.x;
  const int wv = t >> 6;
  const int lane = t & 63;
  const int rloc = lane & 15;
  const int g = lane >> 4;
  const int i_base = bx * 256 + wv * 32;

  __shared__ u16 wt[2][64 * 128];   // [buf][row*128 + unit*8], XOR-swizzled
  __shared__ u32 mk[256 * 36];      // [row][36 words] (32 used, pad 4)

  const float md = __uint_as_float(maxd_u[h]) - DBIAS;
  const float si0 = s_src[(size_t)h * NN + i_base + rloc];
  const float si1 = s_src[(size_t)h * NN + i_base + 16 + rloc];
  const float e00 = si0 + md, e01 = si1 + md;
  const float m0 = fmaxf(e00, NEG_SLOPE * e00);
  const float m1 = fmaxf(e01, NEG_SLOPE * e01);
  const float sa0 = si0 - m0, sb0 = fmaf(NEG_SLOPE, si0, -m0);
  const float sa1 = si1 - m1, sb1 = fmaf(NEG_SLOPE, si1, -m1);

  const float* dg = d_dst + (size_t)h * NN + jq * 1024;
  const u16* wsrc = WxT + (size_t)(h * HD) * NN + jq * 1024;

  const int r0 = t >> 4;
  const int un = t & 15;
  const int up = un ^ (r0 & 7);

#pragma unroll
  for (int k = 0; k < 4; ++k) {
    const int n = k * 512 + t;
    const int row = n >> 3;
    const int quad = n & 7;
    const uint4 mv = *reinterpret_cast<const uint4*>(
        mask + ((size_t)(bx * 256 + row) * (NN / 8)) + jq * 128 + quad * 16);
    *reinterpret_cast<uint4*>(&mk[row * 36 + quad * 4]) = mv;
  }
  {
    const uint4 s0 = *reinterpret_cast<const uint4*>(wsrc + (size_t)r0 * NN + un * 8);
    const uint4 s1 = *reinterpret_cast<const uint4*>(wsrc + (size_t)(r0 + 32) * NN + un * 8);
    *reinterpret_cast<uint4*>(&wt[0][r0 * 128 + up * 8]) = s0;
    *reinterpret_cast<uint4*>(&wt[0][(r0 + 32) * 128 + up * 8]) = s1;
  }
  __syncthreads();

  f32x4 acc0[4] = {}, acc1[4] = {};
  f32x4 accs0 = {}, accs1 = {};
  short8 ones;
#pragma unroll
  for (int e = 0; e < 8; ++e) ones[e] = (short)0x3F80;

  int buf = 0;
  for (int tile = 0; tile < 8; ++tile) {
    uint4 n0, n1;
    const bool pf = (tile < 7);
    if (pf) {
      n0 = *reinterpret_cast<const uint4*>(
          wsrc + (size_t)r0 * NN + (tile + 1) * 128 + un * 8);
      n1 = *reinterpret_cast<const uint4*>(
          wsrc + (size_t)(r0 + 32) * NN + (tile + 1) * 128 + un * 8);
    }

    const uint4 mq0 = *reinterpret_cast<const uint4*>(
        &mk[(wv * 32 + rloc) * 36 + tile * 4]);
    const uint4 mq1 = *reinterpret_cast<const uint4*>(
        &mk[(wv * 32 + 16 + rloc) * 36 + tile * 4]);
#pragma unroll
    for (int ks = 0; ks < 4; ++ks) {
      short8 bfr[4];
#pragma unroll
      for (int dt = 0; dt < 4; ++dt) {
        const int row = dt * 16 + rloc;
        const int unit = (ks * 4 + g) ^ (row & 7);
        bfr[dt] = *reinterpret_cast<const short8*>(&wt[buf][row * 128 + unit * 8]);
      }
      const int jloc = tile * 128 + ks * 32 + g * 8;
      const float4 d0 = *reinterpret_cast<const float4*>(dg + jloc);
      const float4 d1 = *reinterpret_cast<const float4*>(dg + jloc + 4);
      const float dvv[8] = {d0.x, d0.y, d0.z, d0.w, d1.x, d1.y, d1.z, d1.w};
      const u32 mw0 = (ks == 0) ? mq0.x : (ks == 1) ? mq0.y : (ks == 2) ? mq0.z : mq0.w;
      const u32 mw1 = (ks == 0) ? mq1.x : (ks == 1) ? mq1.y : (ks == 2) ? mq1.z : mq1.w;
      const u32 mb0 = (mw0 >> (g * 8)) & 0xffu;
      const u32 mb1 = (mw1 >> (g * 8)) & 0xffu;
      short8 af0, af1;
#pragma unroll
      for (int e = 0; e < 8; ++e) {
        const float dj = dvv[e];
        float x0 = fmaxf(sa0 + dj, fmaf(NEG_SLOPE, dj, sb0));
        float x1 = fmaxf(sa1 + dj, fmaf(NEG_SLOPE, dj, sb1));
        x0 = (mb0 & (1u << e)) ? x0 : -400.f;
        x1 = (mb1 & (1u << e)) ? x1 : -400.f;
        float p0, p1;
        asm("v_exp_f32 %0, %1" : "=v"(p0) : "v"(x0));
        asm("v_exp_f32 %0, %1" : "=v"(p1) : "v"(x1));
        __hip_bfloat16 b0 = __float2bfloat16(p0);
        __hip_bfloat16 b1 = __float2bfloat16(p1);
        af0[e] = *reinterpret_cast<const short*>(&b0);
        af1[e] = *reinterpret_cast<const short*>(&b1);
      }
#pragma unroll
      for (int dt = 0; dt < 4; ++dt) {
        acc0[dt] = __builtin_amdgcn_mfma_f32_16x16x32_bf16(af0, bfr[dt], acc0[dt], 0, 0, 0);
        acc1[dt] = __builtin_amdgcn_mfma_f32_16x16x32_bf16(af1, bfr[dt], acc1[dt], 0, 0, 0);
      }
      accs0 = __builtin_amdgcn_mfma_f32_16x16x32_bf16(af0, ones, accs0, 0, 0, 0);
      accs1 = __builtin_amdgcn_mfma_f32_16x16x32_bf16(af1, ones, accs1, 0, 0, 0);
    }

    if (pf) {
      *reinterpret_cast<uint4*>(&wt[buf ^ 1][r0 * 128 + up * 8]) = n0;
      *reinterpret_cast<uint4*>(&wt[buf ^ 1][(r0 + 32) * 128 + up * 8]) = n1;
    }
    __syncthreads();
    buf ^= 1;
  }

  u16* Pb = Pp + (size_t)jq * NN * OUT_DIM;
#pragma unroll
  for (int dt = 0; dt < 4; ++dt)
#pragma unroll
    for (int q = 0; q < 4; ++q) {
      __hip_bfloat16 v0 = __float2bfloat16(acc0[dt][q]);
      __hip_bfloat16 v1 = __float2bfloat16(acc1[dt][q]);
      Pb[(size_t)(i_base + g * 4 + q) * OUT_DIM + h * HD + dt * 16 + rloc] =
          *reinterpret_cast<const u16*>(&v0);
      Pb[(size_t)(i_base + 16 + g * 4 + q) * OUT_DIM + h * HD + dt * 16 + rloc] =
          *reinterpret_cast<const u16*>(&v1);
    }
  if (rloc == 0) {
    *reinterpret_cast<f32x4*>(&Sp[((size_t)jq * NH + h) * NN + i_base + g * 4]) = accs0;
    *reinterpret_cast<f32x4*>(&Sp[((size_t)jq * NH + h) * NN + i_base + 16 + g * 4]) = accs1;
  }
}

// ---------------------------------------------------------------------------
// K4: merge 4 j-quarter partials, normalize, ELU, LayerNorm, store.
// ---------------------------------------------------------------------------
__global__ __launch_bounds__(256) void k4_final(
    const u16* __restrict__ Pp, const float* __restrict__ Sp,
    const float* __restrict__ gamma, const float* __restrict__ beta,
    float* __restrict__ out)
{
  const int i0 = blockIdx.x * 16;
  const int t = threadIdx.x;
  const int wv = t >> 6;
  const int lane = t & 63;
  const int c0 = lane * 4;
  const int h = lane >> 4;

  const float4 gm = *reinterpret_cast<const float4*>(gamma + c0);
  const float4 bt = *reinterpret_cast<const float4*>(beta + c0);

  for (int rr = 0; rr < 4; ++rr) {
    const int i = i0 + wv * 4 + rr;
    float v[4] = {0.f, 0.f, 0.f, 0.f};
    float denom = 0.f;
#pragma unroll
    for (int q = 0; q < 4; ++q) {
      const ushort4 pv = *reinterpret_cast<const ushort4*>(
          Pp + (size_t)q * NN * OUT_DIM + (size_t)i * OUT_DIM + c0);
      v[0] += __uint_as_float((u32)pv.x << 16);
      v[1] += __uint_as_float((u32)pv.y << 16);
      v[2] += __uint_as_float((u32)pv.z << 16);
      v[3] += __uint_as_float((u32)pv.w << 16);
      denom += Sp[((size_t)q * NH + h) * NN + i];
    }
    const float inv = 1.f / denom;
    float sum = 0.f, sq = 0.f;
#pragma unroll
    for (int q2 = 0; q2 < 4; ++q2) {
      float xx = v[q2] * inv;
      xx = (xx > 0.f) ? xx : expm1f(xx);
      v[q2] = xx;
      sum += xx;
      sq += xx * xx;
    }
#pragma unroll
    for (int mm = 32; mm >= 1; mm >>= 1) {
      sum += __shfl_xor(sum, mm);
      sq += __shfl_xor(sq, mm);
    }
    const float mu = sum * (1.f / OUT_DIM);
    const float var = sq * (1.f / OUT_DIM) - mu * mu;
    const float rs = rsqrtf(var + LN_EPS);
    float4 o;
    o.x = (v[0] - mu) * rs * gm.x + bt.x;
    o.y = (v[1] - mu) * rs * gm.y + bt.y;
    o.z = (v[2] - mu) * rs * gm.z + bt.z;
    o.w = (v[3] - mu) * rs * gm.w + bt.w;
    *reinterpret_cast<float4*>(out + (size_t)i * OUT_DIM + c0) = o;
  }
}

extern "C" void kernel_launch(void* const* d_in, const int* in_sizes, int n_in,
                              void* d_out, int out_size, void* d_ws, size_t ws_size,
                              hipStream_t stream) {
  const float* x = (const float*)d_in[0];
  const int* adj = (const int*)d_in[1];
  const float* W = (const float*)d_in[2];
  const float* a = (const float*)d_in[3];
  const float* gamma = (const float*)d_in[4];
  const float* beta = (const float*)d_in[5];
  float* out = (float*)d_out;

  char* ws = (char*)d_ws;
  size_t off = 0;
  u16* WxT = (u16*)(ws + off);        off += (size_t)NH * HD * NN * 2;          // 2 MiB
  float* s_src = (float*)(ws + off);  off += (size_t)NH * NN * 4;               // 64 KiB
  float* d_dst = (float*)(ws + off);  off += (size_t)NH * NN * 4;               // 64 KiB
  u32* maxd_u = (u32*)(ws + off);     off += 256;
  u8* mask = (u8*)(ws + off);         off += (size_t)NN * (NN / 8);             // 2 MiB
  u16* Pp = (u16*)(ws + off);         off += (size_t)4 * NN * OUT_DIM * 2;      // 8 MiB (bf16)
  float* Sp = (float*)(ws + off);     off += (size_t)4 * NH * NN * 4;           // 256 KiB
  u16* Wt = (u16*)(ws + off);         off += (size_t)NH * HD * IN_DIM * 2;      // 256 KiB

  k0_pack<<<dim3(512), dim3(1024), 0, stream>>>(adj, mask, W, Wt, maxd_u);
  k1_proj<<<dim3(256), dim3(256), 0, stream>>>(x, Wt, a, WxT, s_src, d_dst, maxd_u);
  k3_attn<<<dim3(16, NH, 4), dim3(512), 0, stream>>>(mask, WxT, s_src, d_dst,
                                                     maxd_u, Pp, Sp);
  k4_final<<<dim3(256), dim3(256), 0, stream>>>(Pp, Sp, gamma, beta, out);
}

// Round 10
// 67.403 us; speedup vs baseline: 1.1156x; 1.0100x over previous
//
#include <hip/hip_runtime.h>
#include <hip/hip_bf16.h>

#define NN 4096
#define IN_DIM 512
#define OUT_DIM 256
#define NH 4
#define HD 64
#define NEG_SLOPE 0.2f
#define LN_EPS 1e-5f
#define LOG2E 1.4426950408889634f
#define DBIAS 1024.0f

typedef __attribute__((ext_vector_type(8))) short short8;
typedef __attribute__((ext_vector_type(4))) float f32x4;
typedef unsigned short u16;
typedef unsigned int u32;
typedef unsigned char u8;

// ---------------------------------------------------------------------------
// K0: pack (adj>0)|I into bitmask [NN][NN/8 B]; blocks < 128 also transpose
// W [H][K][D] f32 -> Wt [h*64+d][512] bf16. Block 0 zeroes maxd_u.
// ---------------------------------------------------------------------------
__global__ __launch_bounds__(1024) void k0_pack(
    const int* __restrict__ adj, u8* __restrict__ mask,
    const float* __restrict__ W, u16* __restrict__ Wt,
    u32* __restrict__ maxd_u)
{
  const int b = blockIdx.x;
  const int t = threadIdx.x;
  if (b == 0 && t < NH) maxd_u[t] = 0u;
#pragma unroll
  for (int it = 0; it < 4; ++it) {
    const int row = b * 8 + it * 2 + (t >> 9);
    const int byte = t & 511;
    const int j0 = byte * 8;
    const int4 v0 = *reinterpret_cast<const int4*>(adj + (size_t)row * NN + j0);
    const int4 v1 = *reinterpret_cast<const int4*>(adj + (size_t)row * NN + j0 + 4);
    const int vv[8] = {v0.x, v0.y, v0.z, v0.w, v1.x, v1.y, v1.z, v1.w};
    u32 bbits = 0;
#pragma unroll
    for (int c = 0; c < 8; ++c)
      if ((vv[c] > 0) || (row == j0 + c)) bbits |= (1u << c);
    mask[(size_t)row * (NN / 8) + byte] = (u8)bbits;
  }
  if (b < 128) {
    const int n = b * 1024 + t;      // n = h*2^15 + k*2^6 + d
    const int d = n & 63;
    const int k = (n >> 6) & 511;
    const int h = n >> 15;
    __hip_bfloat16 bv = __float2bfloat16(W[n]);
    Wt[(size_t)(h * HD + d) * IN_DIM + k] = *reinterpret_cast<const u16*>(&bv);
  }
}

// ---------------------------------------------------------------------------
// K1: MFMA projection, all-LDS, dt-split for occupancy.
// grid 256 = (head h = b>>6, 64-row tile), block 512 = 8 waves:
// wave = (rs = wv&3 -> rows rs*16..+16, dh = wv>>2 -> d cols dh*32..+32).
// Stage x tile (64x512 bf16) + Wt head-slice (64x512 bf16) in LDS
// (XOR-swizzled 16B units); 1 barrier; 16 K-steps of {1 A ds_read +
// 2 B ds_read + 2 MFMA}. Score dots need all 64 d: dh=1 partials via
// tiny LDS + barrier; dh=0 finishes (stores + atomicMax maxd).
// LDS = 128.5 KiB, 8 waves/CU (2/SIMD).
// ---------------------------------------------------------------------------
__global__ __launch_bounds__(512) void k1_proj(
    const float* __restrict__ x, const u16* __restrict__ Wt,
    const float* __restrict__ a,
    u16* __restrict__ WxT,
    float* __restrict__ s_src,
    float* __restrict__ d_dst,
    u32* __restrict__ maxd_u)
{
  const int b = blockIdx.x;
  const int h = b >> 6;
  const int i0 = (b & 63) * 64;
  const int t = threadIdx.x;
  const int wv = t >> 6;
  const int lane = t & 63;
  const int rloc = lane & 15;
  const int g = lane >> 4;
  const int rs = wv & 3;
  const int dh = wv >> 2;

  __shared__ u16 xl[64 * 512];   // 64 KiB
  __shared__ u16 wb[64 * 512];   // 64 KiB
  __shared__ float sred_s[64];
  __shared__ float sred_d[64];

  // ---- stage: wave handles 8 rows; lane = 16B unit ----
  {
    const int u = lane;
#pragma unroll
    for (int jj = 0; jj < 8; ++jj) {
      const int r = wv * 8 + jj;
      const int phys = (u & 56) | ((u & 7) ^ (r & 7));
      const float* xr = x + (size_t)(i0 + r) * IN_DIM + u * 8;
      const float4 lo = *reinterpret_cast<const float4*>(xr);
      const float4 hi = *reinterpret_cast<const float4*>(xr + 4);
      const float fv[8] = {lo.x, lo.y, lo.z, lo.w, hi.x, hi.y, hi.z, hi.w};
      u16 us[8];
#pragma unroll
      for (int e = 0; e < 8; ++e) {
        __hip_bfloat16 bv = __float2bfloat16(fv[e]);
        us[e] = *reinterpret_cast<const u16*>(&bv);
      }
      uint4 pk;
      pk.x = (u32)us[0] | ((u32)us[1] << 16);
      pk.y = (u32)us[2] | ((u32)us[3] << 16);
      pk.z = (u32)us[4] | ((u32)us[5] << 16);
      pk.w = (u32)us[6] | ((u32)us[7] << 16);
      *reinterpret_cast<uint4*>(&xl[r * 512 + phys * 8]) = pk;
      const uint4 wsv = *reinterpret_cast<const uint4*>(
          Wt + (size_t)(h * HD + r) * IN_DIM + u * 8);
      *reinterpret_cast<uint4*>(&wb[r * 512 + phys * 8]) = wsv;
    }
  }
  __syncthreads();

  // ---- MFMA loop: 16 rows x 32 cols per wave ----
  f32x4 acc[2] = {};
  const int rbase = rs * 16;
#pragma unroll
  for (int ks = 0; ks < 16; ++ks) {
    const int u = ks * 4 + g;
    const int ar = rbase + rloc;
    const int aphys = (u & 56) | ((u & 7) ^ (ar & 7));
    const short8 af = *reinterpret_cast<const short8*>(&xl[ar * 512 + aphys * 8]);
#pragma unroll
    for (int d2 = 0; d2 < 2; ++d2) {
      const int br = (dh * 2 + d2) * 16 + rloc;
      const int bphys = (u & 56) | ((u & 7) ^ (br & 7));
      const short8 bf = *reinterpret_cast<const short8*>(&wb[br * 512 + bphys * 8]);
      acc[d2] = __builtin_amdgcn_mfma_f32_16x16x32_bf16(af, bf, acc[d2], 0, 0, 0);
    }
  }

  // ---- WxT direct store (acc[d2][q] = C[i=rbase+g*4+q][d=(dh*2+d2)*16+rloc]) ----
#pragma unroll
  for (int d2 = 0; d2 < 2; ++d2) {
    u16 us[4];
#pragma unroll
    for (int q = 0; q < 4; ++q) {
      __hip_bfloat16 bv = __float2bfloat16(acc[d2][q]);
      us[q] = *reinterpret_cast<const u16*>(&bv);
    }
    ushort4 pk = {us[0], us[1], us[2], us[3]};
    *reinterpret_cast<ushort4*>(
        WxT + (size_t)(h * HD + (dh * 2 + d2) * 16 + rloc) * NN + i0 + rbase + g * 4) = pk;
  }

  // ---- score partial dots (this wave's 32 d's) ----
  float as_v[2], ad_v[2];
#pragma unroll
  for (int d2 = 0; d2 < 2; ++d2) {
    as_v[d2] = a[(size_t)h * 2 * HD + (dh * 2 + d2) * 16 + rloc];
    ad_v[d2] = a[(size_t)h * 2 * HD + HD + (dh * 2 + d2) * 16 + rloc];
  }
  float sv[4], dv[4];
#pragma unroll
  for (int q = 0; q < 4; ++q) {
    float s = 0.f, d = 0.f;
#pragma unroll
    for (int d2 = 0; d2 < 2; ++d2) {
      s = fmaf(acc[d2][q], as_v[d2], s);
      d = fmaf(acc[d2][q], ad_v[d2], d);
    }
    sv[q] = s; dv[q] = d;
  }
#pragma unroll
  for (int mm = 8; mm >= 1; mm >>= 1) {
#pragma unroll
    for (int q = 0; q < 4; ++q) {
      sv[q] += __shfl_xor(sv[q], mm);
      dv[q] += __shfl_xor(dv[q], mm);
    }
  }
  if (dh == 1 && rloc == 0) {
#pragma unroll
    for (int q = 0; q < 4; ++q) {
      sred_s[rbase + g * 4 + q] = sv[q];
      sred_d[rbase + g * 4 + q] = dv[q];
    }
  }
  __syncthreads();
  if (dh == 0) {
    float dtt[4];
#pragma unroll
    for (int q = 0; q < 4; ++q) {
      const int row = rbase + g * 4 + q;
      const float st = sv[q] + sred_s[row];
      dtt[q] = dv[q] + sred_d[row];
      if (rloc == 0) {
        s_src[(size_t)h * NN + i0 + row] = st * LOG2E;
        d_dst[(size_t)h * NN + i0 + row] = dtt[q] * LOG2E;
      }
    }
    float dm = fmaxf(fmaxf(dtt[0], dtt[1]), fmaxf(dtt[2], dtt[3])) * LOG2E + DBIAS;
    dm = fmaxf(dm, __shfl_xor(dm, 16));
    dm = fmaxf(dm, __shfl_xor(dm, 32));
    if (lane == 0) atomicMax(maxd_u + h, __float_as_uint(dm));
  }
}

// ---------------------------------------------------------------------------
// K3: masked rank-1 softmax (log2 domain) + PV (bf16 MFMA), LDS-staged &
// double-buffered. grid (16 i-blocks, 4 heads, 8 j-eighths), block 512 =
// 8 waves x 32 rows. j-window 512 = 4 tiles of 128. LDS 52 KB ->
// 2 blocks/CU = 16 waves/CU (VGPR capped via launch_bounds(512,4)).
// Inner math identical to verified round-7 loop.
// ---------------------------------------------------------------------------
__global__ __launch_bounds__(512, 4) void k3_attn(
    const u8* __restrict__ mask,
    const u16* __restrict__ WxT,
    const float* __restrict__ s_src, const float* __restrict__ d_dst,
    const u32* __restrict__ maxd_u,
    u16* __restrict__ Pp, float* __restrict__ Sp)
{
  const int bx = blockIdx.x;
  const int h = blockIdx.y;
  const int jq = blockIdx.z;           // 0..7, window of 512 j
  const int t = threadIdx.x;
  const int wv = t >> 6;
  const int lane = t & 63;
  const int rloc = lane & 15;
  const int g = lane >> 4;
  const int i_base = bx * 256 + wv * 32;

  __shared__ u16 wt[2][64 * 128];   // 32 KiB, XOR-swizzled
  __shared__ u32 mk[256 * 20];      // 20 KiB: [row][20 words] (16 used, pad 4)

  const float md = __uint_as_float(maxd_u[h]) - DBIAS;
  const float si0 = s_src[(size_t)h * NN + i_base + rloc];
  const float si1 = s_src[(size_t)h * NN + i_base + 16 + rloc];
  const float e00 = si0 + md, e01 = si1 + md;
  const float m0 = fmaxf(e00, NEG_SLOPE * e00);
  const float m1 = fmaxf(e01, NEG_SLOPE * e01);
  const float sa0 = si0 - m0, sb0 = fmaf(NEG_SLOPE, si0, -m0);
  const float sa1 = si1 - m1, sb1 = fmaf(NEG_SLOPE, si1, -m1);

  const float* dg = d_dst + (size_t)h * NN + jq * 512;
  const u16* wsrc = WxT + (size_t)(h * HD) * NN + jq * 512;

  const int r0 = t >> 4;
  const int un = t & 15;
  const int up = un ^ (r0 & 7);

  // ---- prologue: mask (once) + WxT tile 0 ----
#pragma unroll
  for (int k = 0; k < 2; ++k) {
    const int n = k * 512 + t;      // 1024 uint4 = 256 rows x 4 quads
    const int row = n >> 2;
    const int quad = n & 3;
    const uint4 mv = *reinterpret_cast<const uint4*>(
        mask + ((size_t)(bx * 256 + row) * (NN / 8)) + jq * 64 + quad * 16);
    *reinterpret_cast<uint4*>(&mk[row * 20 + quad * 4]) = mv;
  }
  {
    const uint4 s0 = *reinterpret_cast<const uint4*>(wsrc + (size_t)r0 * NN + un * 8);
    const uint4 s1 = *reinterpret_cast<const uint4*>(wsrc + (size_t)(r0 + 32) * NN + un * 8);
    *reinterpret_cast<uint4*>(&wt[0][r0 * 128 + up * 8]) = s0;
    *reinterpret_cast<uint4*>(&wt[0][(r0 + 32) * 128 + up * 8]) = s1;
  }
  __syncthreads();

  f32x4 acc0[4] = {}, acc1[4] = {};
  f32x4 accs0 = {}, accs1 = {};
  short8 ones;
#pragma unroll
  for (int e = 0; e < 8; ++e) ones[e] = (short)0x3F80;

  int buf = 0;
  for (int tile = 0; tile < 4; ++tile) {
    uint4 n0, n1;
    const bool pf = (tile < 3);
    if (pf) {
      n0 = *reinterpret_cast<const uint4*>(
          wsrc + (size_t)r0 * NN + (tile + 1) * 128 + un * 8);
      n1 = *reinterpret_cast<const uint4*>(
          wsrc + (size_t)(r0 + 32) * NN + (tile + 1) * 128 + un * 8);
    }

    const uint4 mq0 = *reinterpret_cast<const uint4*>(
        &mk[(wv * 32 + rloc) * 20 + tile * 4]);
    const uint4 mq1 = *reinterpret_cast<const uint4*>(
        &mk[(wv * 32 + 16 + rloc) * 20 + tile * 4]);
#pragma unroll
    for (int ks = 0; ks < 4; ++ks) {
      short8 bfr[4];
#pragma unroll
      for (int dt = 0; dt < 4; ++dt) {
        const int row = dt * 16 + rloc;
        const int unit = (ks * 4 + g) ^ (row & 7);
        bfr[dt] = *reinterpret_cast<const short8*>(&wt[buf][row * 128 + unit * 8]);
      }
      const int jloc = tile * 128 + ks * 32 + g * 8;
      const float4 d0 = *reinterpret_cast<const float4*>(dg + jloc);
      const float4 d1 = *reinterpret_cast<const float4*>(dg + jloc + 4);
      const float dvv[8] = {d0.x, d0.y, d0.z, d0.w, d1.x, d1.y, d1.z, d1.w};
      const u32 mw0 = (ks == 0) ? mq0.x : (ks == 1) ? mq0.y : (ks == 2) ? mq0.z : mq0.w;
      const u32 mw1 = (ks == 0) ? mq1.x : (ks == 1) ? mq1.y : (ks == 2) ? mq1.z : mq1.w;
      const u32 mb0 = (mw0 >> (g * 8)) & 0xffu;
      const u32 mb1 = (mw1 >> (g * 8)) & 0xffu;
      short8 af0, af1;
#pragma unroll
      for (int e = 0; e < 8; ++e) {
        const float dj = dvv[e];
        float x0 = fmaxf(sa0 + dj, fmaf(NEG_SLOPE, dj, sb0));
        float x1 = fmaxf(sa1 + dj, fmaf(NEG_SLOPE, dj, sb1));
        x0 = (mb0 & (1u << e)) ? x0 : -400.f;
        x1 = (mb1 & (1u << e)) ? x1 : -400.f;
        float p0, p1;
        asm("v_exp_f32 %0, %1" : "=v"(p0) : "v"(x0));
        asm("v_exp_f32 %0, %1" : "=v"(p1) : "v"(x1));
        __hip_bfloat16 b0 = __float2bfloat16(p0);
        __hip_bfloat16 b1 = __float2bfloat16(p1);
        af0[e] = *reinterpret_cast<const short*>(&b0);
        af1[e] = *reinterpret_cast<const short*>(&b1);
      }
#pragma unroll
      for (int dt = 0; dt < 4; ++dt) {
        acc0[dt] = __builtin_amdgcn_mfma_f32_16x16x32_bf16(af0, bfr[dt], acc0[dt], 0, 0, 0);
        acc1[dt] = __builtin_amdgcn_mfma_f32_16x16x32_bf16(af1, bfr[dt], acc1[dt], 0, 0, 0);
      }
      accs0 = __builtin_amdgcn_mfma_f32_16x16x32_bf16(af0, ones, accs0, 0, 0, 0);
      accs1 = __builtin_amdgcn_mfma_f32_16x16x32_bf16(af1, ones, accs1, 0, 0, 0);
    }

    if (pf) {
      *reinterpret_cast<uint4*>(&wt[buf ^ 1][r0 * 128 + up * 8]) = n0;
      *reinterpret_cast<uint4*>(&wt[buf ^ 1][(r0 + 32) * 128 + up * 8]) = n1;
    }
    __syncthreads();
    buf ^= 1;
  }

  u16* Pb = Pp + (size_t)jq * NN * OUT_DIM;
#pragma unroll
  for (int dt = 0; dt < 4; ++dt)
#pragma unroll
    for (int q = 0; q < 4; ++q) {
      __hip_bfloat16 v0 = __float2bfloat16(acc0[dt][q]);
      __hip_bfloat16 v1 = __float2bfloat16(acc1[dt][q]);
      Pb[(size_t)(i_base + g * 4 + q) * OUT_DIM + h * HD + dt * 16 + rloc] =
          *reinterpret_cast<const u16*>(&v0);
      Pb[(size_t)(i_base + 16 + g * 4 + q) * OUT_DIM + h * HD + dt * 16 + rloc] =
          *reinterpret_cast<const u16*>(&v1);
    }
  if (rloc == 0) {
    *reinterpret_cast<f32x4*>(&Sp[((size_t)jq * NH + h) * NN + i_base + g * 4]) = accs0;
    *reinterpret_cast<f32x4*>(&Sp[((size_t)jq * NH + h) * NN + i_base + 16 + g * 4]) = accs1;
  }
}

// ---------------------------------------------------------------------------
// K4: merge 8 j-eighth partials, normalize, ELU, LayerNorm, store.
// ---------------------------------------------------------------------------
__global__ __launch_bounds__(256) void k4_final(
    const u16* __restrict__ Pp, const float* __restrict__ Sp,
    const float* __restrict__ gamma, const float* __restrict__ beta,
    float* __restrict__ out)
{
  const int i0 = blockIdx.x * 16;
  const int t = threadIdx.x;
  const int wv = t >> 6;
  const int lane = t & 63;
  const int c0 = lane * 4;
  const int h = lane >> 4;

  const float4 gm = *reinterpret_cast<const float4*>(gamma + c0);
  const float4 bt = *reinterpret_cast<const float4*>(beta + c0);

  for (int rr = 0; rr < 4; ++rr) {
    const int i = i0 + wv * 4 + rr;
    float v[4] = {0.f, 0.f, 0.f, 0.f};
    float denom = 0.f;
#pragma unroll
    for (int q = 0; q < 8; ++q) {
      const ushort4 pv = *reinterpret_cast<const ushort4*>(
          Pp + (size_t)q * NN * OUT_DIM + (size_t)i * OUT_DIM + c0);
      v[0] += __uint_as_float((u32)pv.x << 16);
      v[1] += __uint_as_float((u32)pv.y << 16);
      v[2] += __uint_as_float((u32)pv.z << 16);
      v[3] += __uint_as_float((u32)pv.w << 16);
      denom += Sp[((size_t)q * NH + h) * NN + i];
    }
    const float inv = 1.f / denom;
    float sum = 0.f, sq = 0.f;
#pragma unroll
    for (int q2 = 0; q2 < 4; ++q2) {
      float xx = v[q2] * inv;
      xx = (xx > 0.f) ? xx : expm1f(xx);
      v[q2] = xx;
      sum += xx;
      sq += xx * xx;
    }
#pragma unroll
    for (int mm = 32; mm >= 1; mm >>= 1) {
      sum += __shfl_xor(sum, mm);
      sq += __shfl_xor(sq, mm);
    }
    const float mu = sum * (1.f / OUT_DIM);
    const float var = sq * (1.f / OUT_DIM) - mu * mu;
    const float rs = rsqrtf(var + LN_EPS);
    float4 o;
    o.x = (v[0] - mu) * rs * gm.x + bt.x;
    o.y = (v[1] - mu) * rs * gm.y + bt.y;
    o.z = (v[2] - mu) * rs * gm.z + bt.z;
    o.w = (v[3] - mu) * rs * gm.w + bt.w;
    *reinterpret_cast<float4*>(out + (size_t)i * OUT_DIM + c0) = o;
  }
}

extern "C" void kernel_launch(void* const* d_in, const int* in_sizes, int n_in,
                              void* d_out, int out_size, void* d_ws, size_t ws_size,
                              hipStream_t stream) {
  const float* x = (const float*)d_in[0];
  const int* adj = (const int*)d_in[1];
  const float* W = (const float*)d_in[2];
  const float* a = (const float*)d_in[3];
  const float* gamma = (const float*)d_in[4];
  const float* beta = (const float*)d_in[5];
  float* out = (float*)d_out;

  char* ws = (char*)d_ws;
  size_t off = 0;
  u16* WxT = (u16*)(ws + off);        off += (size_t)NH * HD * NN * 2;          // 2 MiB
  float* s_src = (float*)(ws + off);  off += (size_t)NH * NN * 4;               // 64 KiB
  float* d_dst = (float*)(ws + off);  off += (size_t)NH * NN * 4;               // 64 KiB
  u32* maxd_u = (u32*)(ws + off);     off += 256;
  u8* mask = (u8*)(ws + off);         off += (size_t)NN * (NN / 8);             // 2 MiB
  u16* Pp = (u16*)(ws + off);         off += (size_t)8 * NN * OUT_DIM * 2;      // 16 MiB (bf16)
  float* Sp = (float*)(ws + off);     off += (size_t)8 * NH * NN * 4;           // 512 KiB
  u16* Wt = (u16*)(ws + off);         off += (size_t)NH * HD * IN_DIM * 2;      // 256 KiB

  k0_pack<<<dim3(512), dim3(1024), 0, stream>>>(adj, mask, W, Wt, maxd_u);
  k1_proj<<<dim3(256), dim3(512), 0, stream>>>(x, Wt, a, WxT, s_src, d_dst, maxd_u);
  k3_attn<<<dim3(16, NH, 8), dim3(512), 0, stream>>>(mask, WxT, s_src, d_dst,
                                                     maxd_u, Pp, Sp);
  k4_final<<<dim3(256), dim3(256), 0, stream>>>(Pp, Sp, gamma, beta, out);
}